// Round 3
// baseline (383.858 us; speedup 1.0000x reference)
//
#include <hip/hip_runtime.h>
#include <math.h>

// ---------------------------------------------------------------------------
// SimpleGCN round 3: packed (src,coef) CSR pairs (one 8B scatter per edge),
// cast fused into GEMM1, unroll-8 gathers, agg2+pool fused via atomics.
// ---------------------------------------------------------------------------

typedef __attribute__((ext_vector_type(4))) float f32x4;
typedef __attribute__((ext_vector_type(8))) short bf16x8;

static __device__ __forceinline__ ushort f2bf(float f) {
    union { float f; uint u; } v{f};
    uint r = (v.u + 0x7FFF + ((v.u >> 16) & 1)) >> 16;
    return (ushort)r;
}
static __device__ __forceinline__ float bflo(uint v) {
    union { uint u; float f; } o{v << 16};
    return o.f;
}
static __device__ __forceinline__ float bfhi(uint v) {
    union { uint u; float f; } o{v & 0xffff0000u};
    return o.f;
}
static __device__ __forceinline__ float bf2f(ushort h) {
    union { uint u; float f; } o{(uint)h << 16};
    return o.f;
}

// ---- degree / dinv -------------------------------------------------------
__global__ __launch_bounds__(256) void k_count(const int* __restrict__ dst, int E,
                                               int* __restrict__ degi) {
    int e = blockIdx.x * 256 + threadIdx.x;
    if (e < E) atomicAdd(&degi[dst[e]], 1);
}

__global__ __launch_bounds__(256) void k_dinv(const int* __restrict__ degi,
                                              float* __restrict__ dinv, int N) {
    int i = blockIdx.x * 256 + threadIdx.x;
    if (i < N) dinv[i] = rsqrtf((float)degi[i] + 1.0f);
}

// ---- 2-level exclusive scan over degi -> rowptr --------------------------
__global__ __launch_bounds__(256) void k_scan1(const int* __restrict__ in,
                                               int* __restrict__ outp,  // rowptr+1
                                               int* __restrict__ bsums, int N) {
    __shared__ int sh[256];
    int t = threadIdx.x, b = blockIdx.x;
    int base = b * 1024 + t * 4;
    int v0 = (base + 0 < N) ? in[base + 0] : 0;
    int v1 = (base + 1 < N) ? in[base + 1] : 0;
    int v2 = (base + 2 < N) ? in[base + 2] : 0;
    int v3 = (base + 3 < N) ? in[base + 3] : 0;
    int l0 = v0, l1 = l0 + v1, l2 = l1 + v2, l3 = l2 + v3;
    sh[t] = l3;
    __syncthreads();
    int run = l3;
    for (int off = 1; off < 256; off <<= 1) {
        int y = (t >= off) ? sh[t - off] : 0;
        __syncthreads();
        run += y;
        sh[t] = run;
        __syncthreads();
    }
    int excl = run - l3;
    if (base + 0 < N) outp[base + 0] = excl + l0;
    if (base + 1 < N) outp[base + 1] = excl + l1;
    if (base + 2 < N) outp[base + 2] = excl + l2;
    if (base + 3 < N) outp[base + 3] = excl + l3;
    if (t == 255) bsums[b] = run;
}

__global__ __launch_bounds__(256) void k_scan2(const int* __restrict__ bsums,
                                               int* __restrict__ boffs, int nb) {
    __shared__ int sh[256];
    int t = threadIdx.x;
    int v = (t < nb) ? bsums[t] : 0;
    sh[t] = v;
    __syncthreads();
    int run = v;
    for (int off = 1; off < 256; off <<= 1) {
        int y = (t >= off) ? sh[t - off] : 0;
        __syncthreads();
        run += y;
        sh[t] = run;
        __syncthreads();
    }
    boffs[t] = run - v;  // exclusive
}

__global__ __launch_bounds__(256) void k_scan3(int* __restrict__ rowptr,
                                               const int* __restrict__ boffs,
                                               int* __restrict__ cursor, int N) {
    int i = blockIdx.x * 256 + threadIdx.x;
    if (i == 0) { rowptr[0] = 0; cursor[0] = 0; }
    if (i < N) {
        int v = rowptr[1 + i] + boffs[i >> 10];
        rowptr[1 + i] = v;
        if (i + 1 < N) cursor[i + 1] = v;
    }
}

// ---- CSR fill: single 8B packed scatter per edge -------------------------
__global__ __launch_bounds__(256) void k_fill(const int* __restrict__ src,
                                              const int* __restrict__ dst,
                                              const float* __restrict__ dinv, int E,
                                              int* __restrict__ cursor,
                                              int2* __restrict__ pairs) {
    int e = blockIdx.x * 256 + threadIdx.x;
    if (e < E) {
        int d = dst[e], s = src[e];
        float c = dinv[s] * dinv[d];
        int p = atomicAdd(&cursor[d], 1);
        int2 pr;
        pr.x = s;
        pr.y = __float_as_int(c);
        pairs[p] = pr;
    }
}

// ---- weight prep: W1[128,128]->w1t (T), W2[128,40]->w2t[48][128] bf16 ----
__global__ __launch_bounds__(256) void k_prep_w(const float* __restrict__ W1,
                                                const float* __restrict__ W2,
                                                ushort* __restrict__ w1t,
                                                ushort* __restrict__ w2t) {
    int i = blockIdx.x * 256 + threadIdx.x;
    if (i < 128 * 128) {
        int n = i >> 7, k = i & 127;
        w1t[i] = f2bf(W1[k * 128 + n]);
    } else if (i < 128 * 128 + 48 * 128) {
        int j = i - 128 * 128;
        int n = j >> 7, k = j & 127;
        w2t[j] = (n < 40) ? f2bf(W2[k * 40 + n]) : (ushort)0;
    }
}

// ---- GEMM1: A fp32 [M,128] (cast in staging) @ BT bf16 -> C bf16 ---------
template <int NF>
__global__ __launch_bounds__(256) void k_gemm_f32a(const float* __restrict__ A,
                                                   const ushort* __restrict__ BT,
                                                   ushort* __restrict__ C, int M,
                                                   int NCOLS) {
    __shared__ ushort As[64][136];
    __shared__ ushort Bs[NF * 16][136];
    const int tid = threadIdx.x;
    const int m0 = blockIdx.x * 64;
#pragma unroll
    for (int i = 0; i < 4; i++) {  // 1024 chunks of 8 elems (fp32 -> bf16)
        int chunk = tid + i * 256;
        int r = chunk >> 4, c8 = chunk & 15;
        float4 v0 = {0.f, 0.f, 0.f, 0.f}, v1 = {0.f, 0.f, 0.f, 0.f};
        if (m0 + r < M) {
            const float* p = &A[(size_t)(m0 + r) * 128 + c8 * 8];
            v0 = *(const float4*)p;
            v1 = *(const float4*)(p + 4);
        }
        ushort o[8];
        o[0] = f2bf(v0.x); o[1] = f2bf(v0.y); o[2] = f2bf(v0.z); o[3] = f2bf(v0.w);
        o[4] = f2bf(v1.x); o[5] = f2bf(v1.y); o[6] = f2bf(v1.z); o[7] = f2bf(v1.w);
        *(float4*)&As[r][c8 * 8] = *(float4*)o;
    }
#pragma unroll
    for (int i = 0; i < NF; i++) {  // stage B: NF*16 rows x 16 chunks
        int chunk = tid + i * 256;
        int r = chunk >> 4, c = chunk & 15;
        *(float4*)&Bs[r][c * 8] = *(const float4*)&BT[(size_t)r * 128 + c * 8];
    }
    __syncthreads();
    const int wave = tid >> 6, lane = tid & 63;
    const int arow = wave * 16 + (lane & 15);
    const int kgrp = (lane >> 4) * 8;
    f32x4 acc[NF];
#pragma unroll
    for (int i = 0; i < NF; i++) acc[i] = (f32x4){0.f, 0.f, 0.f, 0.f};
#pragma unroll
    for (int kk = 0; kk < 4; kk++) {
        bf16x8 a = *(const bf16x8*)&As[arow][kk * 32 + kgrp];
#pragma unroll
        for (int nf = 0; nf < NF; nf++) {
            bf16x8 b = *(const bf16x8*)&Bs[nf * 16 + (lane & 15)][kk * 32 + kgrp];
            acc[nf] = __builtin_amdgcn_mfma_f32_16x16x32_bf16(a, b, acc[nf], 0, 0, 0);
        }
    }
    const int orow = m0 + wave * 16 + (lane >> 4) * 4;
#pragma unroll
    for (int nf = 0; nf < NF; nf++) {
        int col = nf * 16 + (lane & 15);
        if (col >= NCOLS) continue;
#pragma unroll
        for (int j = 0; j < 4; j++) {
            int r = orow + j;
            if (r < M) C[(size_t)r * NCOLS + col] = f2bf(acc[nf][j]);
        }
    }
}

// ---- GEMM2: A bf16 @ BT bf16 -> C bf16 -----------------------------------
template <int NF>
__global__ __launch_bounds__(256) void k_gemm_bf16(const ushort* __restrict__ A,
                                                   const ushort* __restrict__ BT,
                                                   ushort* __restrict__ C, int M,
                                                   int NCOLS) {
    __shared__ ushort As[64][136];
    __shared__ ushort Bs[NF * 16][136];
    const int tid = threadIdx.x;
    const int m0 = blockIdx.x * 64;
#pragma unroll
    for (int i = 0; i < 4; i++) {
        int chunk = tid + i * 256;
        int r = chunk >> 4, c = chunk & 15;
        float4 v = {0.f, 0.f, 0.f, 0.f};
        if (m0 + r < M) v = *(const float4*)&A[((size_t)(m0 + r)) * 128 + c * 8];
        *(float4*)&As[r][c * 8] = v;
    }
#pragma unroll
    for (int i = 0; i < NF; i++) {
        int chunk = tid + i * 256;
        int r = chunk >> 4, c = chunk & 15;
        *(float4*)&Bs[r][c * 8] = *(const float4*)&BT[(size_t)r * 128 + c * 8];
    }
    __syncthreads();
    const int wave = tid >> 6, lane = tid & 63;
    const int arow = wave * 16 + (lane & 15);
    const int kgrp = (lane >> 4) * 8;
    f32x4 acc[NF];
#pragma unroll
    for (int i = 0; i < NF; i++) acc[i] = (f32x4){0.f, 0.f, 0.f, 0.f};
#pragma unroll
    for (int kk = 0; kk < 4; kk++) {
        bf16x8 a = *(const bf16x8*)&As[arow][kk * 32 + kgrp];
#pragma unroll
        for (int nf = 0; nf < NF; nf++) {
            bf16x8 b = *(const bf16x8*)&Bs[nf * 16 + (lane & 15)][kk * 32 + kgrp];
            acc[nf] = __builtin_amdgcn_mfma_f32_16x16x32_bf16(a, b, acc[nf], 0, 0, 0);
        }
    }
    const int orow = m0 + wave * 16 + (lane >> 4) * 4;
#pragma unroll
    for (int nf = 0; nf < NF; nf++) {
        int col = nf * 16 + (lane & 15);
        if (col >= NCOLS) continue;
#pragma unroll
        for (int j = 0; j < 4; j++) {
            int r = orow + j;
            if (r < M) C[(size_t)r * NCOLS + col] = f2bf(acc[nf][j]);
        }
    }
}

// ---- layer-1 aggregation: packed pairs, unroll 8, one wave/node ----------
__global__ __launch_bounds__(256) void k_agg1(const ushort* __restrict__ h1b,
                                              const int* __restrict__ rowptr,
                                              const int2* __restrict__ pairs,
                                              const float* __restrict__ dinv,
                                              const float* __restrict__ b1,
                                              ushort* __restrict__ outb, int N) {
    int wid = (blockIdx.x * 256 + threadIdx.x) >> 6;
    int lane = threadIdx.x & 63;
    if (wid >= N) return;
    const uint* h1u = (const uint*)h1b;  // 2 bf16 per lane
    int beg = rowptr[wid], end = rowptr[wid + 1];
    float ax = 0.f, ay = 0.f;
    int e = beg;
    for (; e + 8 <= end; e += 8) {
        int2 p0 = pairs[e + 0], p1 = pairs[e + 1], p2 = pairs[e + 2], p3 = pairs[e + 3];
        int2 p4 = pairs[e + 4], p5 = pairs[e + 5], p6 = pairs[e + 6], p7 = pairs[e + 7];
        uint v0 = h1u[(size_t)p0.x * 64 + lane];
        uint v1 = h1u[(size_t)p1.x * 64 + lane];
        uint v2 = h1u[(size_t)p2.x * 64 + lane];
        uint v3 = h1u[(size_t)p3.x * 64 + lane];
        uint v4 = h1u[(size_t)p4.x * 64 + lane];
        uint v5 = h1u[(size_t)p5.x * 64 + lane];
        uint v6 = h1u[(size_t)p6.x * 64 + lane];
        uint v7 = h1u[(size_t)p7.x * 64 + lane];
        float w0 = __int_as_float(p0.y), w1 = __int_as_float(p1.y);
        float w2 = __int_as_float(p2.y), w3 = __int_as_float(p3.y);
        float w4 = __int_as_float(p4.y), w5 = __int_as_float(p5.y);
        float w6 = __int_as_float(p6.y), w7 = __int_as_float(p7.y);
        ax += w0 * bflo(v0) + w1 * bflo(v1) + w2 * bflo(v2) + w3 * bflo(v3);
        ax += w4 * bflo(v4) + w5 * bflo(v5) + w6 * bflo(v6) + w7 * bflo(v7);
        ay += w0 * bfhi(v0) + w1 * bfhi(v1) + w2 * bfhi(v2) + w3 * bfhi(v3);
        ay += w4 * bfhi(v4) + w5 * bfhi(v5) + w6 * bfhi(v6) + w7 * bfhi(v7);
    }
    for (; e < end; ++e) {
        int2 p = pairs[e];
        float w = __int_as_float(p.y);
        uint v = h1u[(size_t)p.x * 64 + lane];
        ax += w * bflo(v);
        ay += w * bfhi(v);
    }
    float dn = dinv[wid];
    uint sv = h1u[(size_t)wid * 64 + lane];
    float ws = dn * dn;
    ax += ws * bflo(sv);
    ay += ws * bfhi(sv);
    float2 bb = *(const float2*)&b1[lane * 2];
    ax = fmaxf(ax + bb.x, 0.f);
    ay = fmaxf(ay + bb.y, 0.f);
    uint packed = ((uint)f2bf(ay) << 16) | (uint)f2bf(ax);
    ((uint*)outb)[(size_t)wid * 64 + lane] = packed;
}

// ---- layer-2 aggregation fused with mean-pool accumulation ---------------
__global__ __launch_bounds__(256) void k_agg2_pool(const ushort* __restrict__ h2b,
                                                   const int* __restrict__ rowptr,
                                                   const int2* __restrict__ pairs,
                                                   const float* __restrict__ dinv,
                                                   const float* __restrict__ b2,
                                                   const int* __restrict__ batch,
                                                   float* __restrict__ pooled, int N,
                                                   int DOUT) {
    int wid = (blockIdx.x * 256 + threadIdx.x) >> 6;
    int lane = threadIdx.x & 63;
    if (wid >= N || lane >= DOUT) return;
    int beg = rowptr[wid], end = rowptr[wid + 1];
    float acc = 0.f;
    int e = beg;
    for (; e + 8 <= end; e += 8) {
        int2 p0 = pairs[e + 0], p1 = pairs[e + 1], p2 = pairs[e + 2], p3 = pairs[e + 3];
        int2 p4 = pairs[e + 4], p5 = pairs[e + 5], p6 = pairs[e + 6], p7 = pairs[e + 7];
        float v0 = bf2f(h2b[(size_t)p0.x * DOUT + lane]);
        float v1 = bf2f(h2b[(size_t)p1.x * DOUT + lane]);
        float v2 = bf2f(h2b[(size_t)p2.x * DOUT + lane]);
        float v3 = bf2f(h2b[(size_t)p3.x * DOUT + lane]);
        float v4 = bf2f(h2b[(size_t)p4.x * DOUT + lane]);
        float v5 = bf2f(h2b[(size_t)p5.x * DOUT + lane]);
        float v6 = bf2f(h2b[(size_t)p6.x * DOUT + lane]);
        float v7 = bf2f(h2b[(size_t)p7.x * DOUT + lane]);
        acc += __int_as_float(p0.y) * v0 + __int_as_float(p1.y) * v1 +
               __int_as_float(p2.y) * v2 + __int_as_float(p3.y) * v3;
        acc += __int_as_float(p4.y) * v4 + __int_as_float(p5.y) * v5 +
               __int_as_float(p6.y) * v6 + __int_as_float(p7.y) * v7;
    }
    for (; e < end; ++e) {
        int2 p = pairs[e];
        acc += __int_as_float(p.y) * bf2f(h2b[(size_t)p.x * DOUT + lane]);
    }
    float dn = dinv[wid];
    acc += dn * dn * bf2f(h2b[(size_t)wid * DOUT + lane]);
    acc = fmaxf(acc + b2[lane], 0.f);
    atomicAdd(&pooled[(size_t)batch[wid] * DOUT + lane], acc);
}

// ---- finish: mean + log_softmax ------------------------------------------
__global__ __launch_bounds__(64) void k_finish(const float* __restrict__ pooled,
                                               const int* __restrict__ batch, int N,
                                               int DOUT, float* __restrict__ out) {
    int g = blockIdx.x;
    int c = threadIdx.x;
    int lo = 0, hi = N;
    while (lo < hi) {
        int mid = (lo + hi) >> 1;
        if (batch[mid] < g) lo = mid + 1; else hi = mid;
    }
    int start = lo;
    hi = N;
    int lo2 = lo;
    while (lo2 < hi) {
        int mid = (lo2 + hi) >> 1;
        if (batch[mid] <= g) lo2 = mid + 1; else hi = mid;
    }
    int cnt = lo2 - start;
    float v = (c < DOUT) ? pooled[(size_t)g * DOUT + c] / fmaxf((float)cnt, 1.f) : -1e30f;
    float m = v;
#pragma unroll
    for (int o = 32; o; o >>= 1) m = fmaxf(m, __shfl_xor(m, o));
    float ex = (c < DOUT) ? expf(v - m) : 0.f;
    float s = ex;
#pragma unroll
    for (int o = 32; o; o >>= 1) s += __shfl_xor(s, o);
    if (c < DOUT) out[(size_t)g * DOUT + c] = (v - m) - logf(s);
}

extern "C" void kernel_launch(void* const* d_in, const int* in_sizes, int n_in,
                              void* d_out, int out_size, void* d_ws, size_t ws_size,
                              hipStream_t stream) {
    const float* x = (const float*)d_in[0];
    const int* src = (const int*)d_in[1];
    const int* dst = (const int*)d_in[2];
    const int* batch = (const int*)d_in[3];
    const float* W1 = (const float*)d_in[4];
    const float* b1 = (const float*)d_in[5];
    const float* W2 = (const float*)d_in[6];
    const float* b2 = (const float*)d_in[7];
    float* out = (float*)d_out;

    const int N = in_sizes[3];
    const int E = in_sizes[1];
    const int DOUT = in_sizes[7];
    const int G = out_size / DOUT;

    char* ws = (char*)d_ws;
    size_t off = 0;
    auto alloc = [&](size_t bytes) -> char* {
        char* p = ws + off;
        off += (bytes + 255) & ~(size_t)255;
        return p;
    };
    ushort* h1b = (ushort*)alloc((size_t)N * 128 * 2);   // reused as h2b
    ushort* hrelu = (ushort*)alloc((size_t)N * 128 * 2);
    int2* pairs = (int2*)alloc((size_t)E * 8);
    int* degi = (int*)alloc((size_t)N * 4);
    int* rowptr = (int*)alloc((size_t)(N + 1) * 4);
    int* cursor = (int*)alloc((size_t)N * 4);
    float* dinv = (float*)alloc((size_t)N * 4);
    int* bsums = (int*)alloc(256 * 4);
    int* boffs = (int*)alloc(256 * 4);
    ushort* w1t = (ushort*)alloc(128 * 128 * 2);
    ushort* w2t = (ushort*)alloc(48 * 128 * 2);
    float* pooled = (float*)alloc((size_t)G * DOUT * 4);

    ushort* h2b = h1b;  // h1b dead after k_agg1

    hipMemsetAsync(degi, 0, (size_t)N * 4, stream);
    hipMemsetAsync(pooled, 0, (size_t)G * DOUT * 4, stream);

    const int TB = 256;
    k_count<<<(E + TB - 1) / TB, TB, 0, stream>>>(dst, E, degi);
    k_dinv<<<(N + TB - 1) / TB, TB, 0, stream>>>(degi, dinv, N);
    int nb = (N + 1023) / 1024;
    k_scan1<<<nb, TB, 0, stream>>>(degi, rowptr + 1, bsums, N);
    k_scan2<<<1, TB, 0, stream>>>(bsums, boffs, nb);
    k_scan3<<<(N + TB - 1) / TB, TB, 0, stream>>>(rowptr, boffs, cursor, N);
    k_fill<<<(E + TB - 1) / TB, TB, 0, stream>>>(src, dst, dinv, E, cursor, pairs);

    k_prep_w<<<(128 * 128 + 48 * 128 + TB - 1) / TB, TB, 0, stream>>>(W1, W2, w1t, w2t);

    // h1b = bf16(x) @ W1
    k_gemm_f32a<8><<<(N + 63) / 64, TB, 0, stream>>>(x, w1t, h1b, N, 128);
    // hrelu = relu(agg(h1b) + b1)
    k_agg1<<<(N + 3) / 4, TB, 0, stream>>>(h1b, rowptr, pairs, dinv, b1, hrelu, N);
    // h2b = hrelu @ W2
    k_gemm_bf16<3><<<(N + 63) / 64, TB, 0, stream>>>(hrelu, w2t, h2b, N, DOUT);
    // pooled += relu(agg(h2b) + b2) per graph
    k_agg2_pool<<<(N + 3) / 4, TB, 0, stream>>>(h2b, rowptr, pairs, dinv, b2, batch,
                                                pooled, N, DOUT);
    // mean + log_softmax
    k_finish<<<G, 64, 0, stream>>>(pooled, batch, N, DOUT, out);
}